// Round 5
// baseline (198798.743 us; speedup 1.0000x reference)
//
#include <hip/hip_runtime.h>
#include <hip/hip_bf16.h>

typedef __hip_bfloat16 bf16;
typedef short s8 __attribute__((ext_vector_type(8)));
typedef short sv4 __attribute__((ext_vector_type(4)));
typedef float f4 __attribute__((ext_vector_type(4)));

#define BETA 0.125f
#define EPS 1e-5f

// ---------- converts ----------
__global__ __launch_bounds__(256) void f2b_k(const float* __restrict__ in, bf16* __restrict__ out, long n){
    long i = (long)blockIdx.x*256 + threadIdx.x;
    if (i < n) out[i] = __float2bfloat16(in[i]);
}
__global__ __launch_bounds__(256) void padx_k(const float* __restrict__ x, bf16* __restrict__ xb){
    long i = (long)blockIdx.x*256 + threadIdx.x;
    if (i >= 6400L*768) return;
    long row = i / 768;
    xb[i] = (row < 6272) ? __float2bfloat16(x[i]) : __float2bfloat16(0.f);
}
__global__ __launch_bounds__(256) void tr_k(const short* __restrict__ Bi, short* __restrict__ Bo){
    __shared__ short t[32][33];
    int i0 = blockIdx.x*32, j0 = blockIdx.y*32;
    int li = threadIdx.x & 31, lj = threadIdx.x >> 5;
    #pragma unroll
    for (int r=0;r<4;r++) t[lj+8*r][li] = Bi[(long)(i0+lj+8*r)*768 + j0+li];
    __syncthreads();
    #pragma unroll
    for (int r=0;r<4;r++) Bo[(long)(j0+lj+8*r)*4608 + i0+li] = t[li][lj+8*r];
}

// ---------- cls row init ----------
__global__ __launch_bounds__(256) void cls_k(const float* __restrict__ cls, const float* __restrict__ pos,
                                             float* __restrict__ t){
    int i = blockIdx.x*256 + threadIdx.x;
    int b = i / 768, c = i % 768;
    t[((long)b*197)*768 + c] = cls[c] + pos[c];
}

// ---------- global-direct MFMA GEMM: C = A[M,K] @ B[N,K]^T ----------
// No LDS, no barriers: each wave owns a 64x64 tile, frags straight from global
// (L2/LLC-resident), register double-buffer prefetch on k.
// MODE 0: C bf16, relu for col>=relu0 | MODE 1: C fp32 atomicAdd (split-K over z)
// MODE 2: encode epilogue | MODE 3: decode epilogue
template<int MODE>
__global__ __launch_bounds__(256) void gg_k(
    const short* __restrict__ A, int lda,
    const short* __restrict__ B, int ldb,
    float* __restrict__ Cf, bf16* __restrict__ Cb, int ldc,
    int K, int relu0,
    const float* __restrict__ bias, const float* __restrict__ pos)
{
    const int tid = threadIdx.x, w = tid>>6, l = tid&63;
    const int m0 = blockIdx.y*128, n0 = blockIdx.x*128;
    const int wm = (w>>1)*64, wn = (w&1)*64;
    const int lr = l&15, lq = l>>4;
    int koff, nk;
    if (MODE==1){ koff = blockIdx.z * (K>>1); nk = K>>6; }
    else        { koff = 0;                   nk = K>>5; }
    const short* pa = A + (size_t)(m0+wm+lr)*lda + koff + lq*8;
    const short* pb = B + (size_t)(n0+wn+lr)*ldb + koff + lq*8;

    f4 acc[4][4] = {};
    s8 ab[2][4], bb[2][4];
    #pragma unroll
    for (int i=0;i<4;i++){
        ab[0][i] = *(const s8*)(pa + (size_t)i*16*lda);
        bb[0][i] = *(const s8*)(pb + (size_t)i*16*ldb);
    }
    #pragma unroll 2
    for (int kt=0; kt<nk; kt++){
        const int cur = kt&1, nxt = cur^1;
        if (kt+1 < nk){
            const int ko = (kt+1)*32;
            #pragma unroll
            for (int i=0;i<4;i++){
                ab[nxt][i] = *(const s8*)(pa + (size_t)i*16*lda + ko);
                bb[nxt][i] = *(const s8*)(pb + (size_t)i*16*ldb + ko);
            }
        }
        #pragma unroll
        for (int i=0;i<4;i++)
            #pragma unroll
            for (int j=0;j<4;j++)
                acc[i][j] = __builtin_amdgcn_mfma_f32_16x16x32_bf16(ab[cur][i], bb[cur][j], acc[i][j], 0,0,0);
    }

    const int er = (l>>4)*4;
    const int ec = l&15;
    #pragma unroll
    for (int i=0;i<4;i++){
        #pragma unroll
        for (int j=0;j<4;j++){
            int gr0 = m0 + wm + i*16 + er;
            int gc  = n0 + wn + j*16 + ec;
            #pragma unroll
            for (int r=0;r<4;r++){
                float v = acc[i][j][r];
                int gr = gr0 + r;
                if (MODE==0){
                    if (gc >= relu0) v = v>0.f ? v : 0.f;
                    Cb[(size_t)gr*ldc + gc] = __float2bfloat16(v);
                } else if (MODE==1){
                    atomicAdd(Cf + (size_t)gr*ldc + gc, v);
                } else if (MODE==2){
                    if (gr < 6272){
                        int b = gr/196, n = gr%196;
                        Cf[((size_t)b*197 + n + 1)*768 + gc] = v + bias[gc] + pos[(long)(n+1)*768+gc];
                    }
                } else {
                    if (gr < 6272) Cf[(size_t)gr*ldc + gc] = v + bias[gc];
                }
            }
        }
    }
}

// ---------- pack q^T / k^T : [384][64 z][256 m] bf16, zero-padded ----------
__global__ __launch_bounds__(256) void pack_k(const short* __restrict__ qkh,
                                              short* __restrict__ qT, short* __restrict__ kT){
    __shared__ short tq[64][65];
    __shared__ short tk[64][65];
    const int bh = blockIdx.x, b = bh/12, h = bh%12;
    const int mc = blockIdx.y*64;
    const int tid = threadIdx.x;
    #pragma unroll
    for (int e=0;e<16;e++){
        int i = tid + e*256; int r = i>>6, c = i&63;
        int mg = mc + r;
        short vq = 0, vk = 0;
        if (mg < 197){
            size_t base = (size_t)(b*197+mg)*4608 + h*64 + c;
            vq = qkh[base]; vk = qkh[base+768];
        }
        tq[r][c] = vq; tk[r][c] = vk;
    }
    __syncthreads();
    #pragma unroll
    for (int e=0;e<16;e++){
        int i = tid + e*256; int zr = i>>6, cm = i&63;
        size_t o = (size_t)bh*16384 + (size_t)zr*256 + mc + cm;
        qT[o] = tq[cm][zr];
        kT[o] = tk[cm][zr];
    }
}

// ---------- fused attention per (b,h) ----------
__global__ __launch_bounds__(256) void attn_k(
    short* __restrict__ qkh, const short* __restrict__ qT, const short* __restrict__ kT)
{
    __shared__ short Pl[64*232];
    __shared__ short Ptl[208*72];
    const int bh = blockIdx.x, b = bh/12, h = bh%12;
    const int tid = threadIdx.x, w = tid>>6, l = tid&63;
    const int lr = l&15, lq = l>>4;
    const size_t qcol = (size_t)h*64, kcol = 768 + qcol;
    const size_t rbase = (size_t)b*197*4608;
    const short* qTp = qT + (size_t)bh*16384;
    const short* kTp = kT + (size_t)bh*16384;

    for (int i=tid; i<64*16; i+=256){ int r=i>>4, c=208+(i&15); Pl[r*232+c]=0; }

    f4 ak[13];
    #pragma unroll
    for (int t=0;t<13;t++) ak[t] = (f4){0.f,0.f,0.f,0.f};

    for (int iter=0; iter<4; iter++){
        const int m0 = iter*64;
        f4 S[13];
        #pragma unroll
        for (int t=0;t<13;t++) S[t] = (f4){0.f,0.f,0.f,0.f};
        const int mrow = m0 + w*16 + lr;
        #pragma unroll
        for (int ks=0; ks<2; ks++){
            s8 af = *(const s8*)(qkh + rbase + (size_t)mrow*4608 + qcol + ks*32 + lq*8);
            #pragma unroll
            for (int t=0;t<13;t++){
                s8 bf = *(const s8*)(qkh + rbase + (size_t)(t*16+lr)*4608 + kcol + ks*32 + lq*8);
                S[t] = __builtin_amdgcn_mfma_f32_16x16x32_bf16(af, bf, S[t], 0,0,0);
            }
        }
        __syncthreads();
        const int mbase = w*16 + lq*4;
        #pragma unroll
        for (int r=0;r<4;r++){
            float mx = -1e30f;
            #pragma unroll
            for (int t=0;t<13;t++){
                float v = S[t][r]*BETA;
                if (t==12 && lr>=5) v = -1e30f;
                S[t][r] = v;
                mx = fmaxf(mx, v);
            }
            mx = fmaxf(mx, __shfl_xor(mx,1,64)); mx = fmaxf(mx, __shfl_xor(mx,2,64));
            mx = fmaxf(mx, __shfl_xor(mx,4,64)); mx = fmaxf(mx, __shfl_xor(mx,8,64));
            float sm = 0.f;
            #pragma unroll
            for (int t=0;t<13;t++){ float e = __expf(S[t][r]-mx); S[t][r]=e; sm+=e; }
            sm += __shfl_xor(sm,1,64); sm += __shfl_xor(sm,2,64);
            sm += __shfl_xor(sm,4,64); sm += __shfl_xor(sm,8,64);
            float inv = 1.f/sm;
            bool valid = (m0 + mbase + r) < 197;
            #pragma unroll
            for (int t=0;t<13;t++) S[t][r] = valid ? S[t][r]*inv : 0.f;
        }
        #pragma unroll
        for (int t=0;t<13;t++){
            int c = t*16 + lr;
            short pb[4];
            #pragma unroll
            for (int r=0;r<4;r++){
                bf16 bv = __float2bfloat16(S[t][r]);
                pb[r] = *(short*)&bv;
                Pl[(mbase+r)*232 + c] = pb[r];
            }
            *(sv4*)(Ptl + c*72 + mbase) = (sv4){pb[0],pb[1],pb[2],pb[3]};
        }
        __syncthreads();
        f4 aq[4];
        #pragma unroll
        for (int t=0;t<4;t++) aq[t] = (f4){0.f,0.f,0.f,0.f};
        #pragma unroll
        for (int ks=0; ks<7; ks++){
            s8 af = *(const s8*)(kTp + (w*16+lr)*256 + ks*32 + lq*8);
            #pragma unroll
            for (int mt=0;mt<4;mt++){
                s8 bf = *(const s8*)(Pl + (mt*16+lr)*232 + ks*32 + lq*8);
                aq[mt] = __builtin_amdgcn_mfma_f32_16x16x32_bf16(af, bf, aq[mt], 0,0,0);
            }
        }
        #pragma unroll
        for (int mt=0;mt<4;mt++){
            int mg = m0 + mt*16 + lr;
            if (mg < 197){
                sv4 pv;
                #pragma unroll
                for (int r=0;r<4;r++){ bf16 bv=__float2bfloat16(aq[mt][r]); pv[r]=*(short*)&bv; }
                *(sv4*)(qkh + rbase + (size_t)mg*4608 + qcol + w*16 + lq*4) = pv;
            }
        }
        #pragma unroll
        for (int ks=0; ks<2; ks++){
            s8 bf = *(const s8*)(qTp + (w*16+lr)*256 + m0 + ks*32 + lq*8);
            #pragma unroll
            for (int t=0;t<13;t++){
                s8 af = *(const s8*)(Ptl + (t*16+lr)*72 + ks*32 + lq*8);
                ak[t] = __builtin_amdgcn_mfma_f32_16x16x32_bf16(af, bf, ak[t], 0,0,0);
            }
        }
    }
    #pragma unroll
    for (int t=0;t<13;t++){
        #pragma unroll
        for (int r=0;r<4;r++){
            int n = t*16 + lq*4 + r;
            if (n < 197)
                *(bf16*)(qkh + rbase + (size_t)n*4608 + kcol + w*16 + lr) = __float2bfloat16(ak[t][r]);
        }
    }
}

// ---------- LN: fp32 in -> bf16 out ----------
__global__ __launch_bounds__(256) void ln_k(
    const float* __restrict__ in, bf16* __restrict__ out,
    const float* __restrict__ scale, const float* __restrict__ bias,
    int scalar_scale, int rowmap)
{
    int r = blockIdx.x;
    long src = rowmap ? ((long)(r/196)*197 + r%196 + 1) : (long)r;
    const float* x = in + src*768;
    int tid = threadIdx.x;
    float v0 = x[tid], v1 = x[tid+256], v2 = x[tid+512];
    __shared__ float red[4];
    float s = v0+v1+v2;
    #pragma unroll
    for (int o=1;o<64;o<<=1) s += __shfl_xor(s, o, 64);
    if ((tid&63)==0) red[tid>>6] = s;
    __syncthreads();
    float mu = (red[0]+red[1]+red[2]+red[3]) * (1.f/768.f);
    float d0=v0-mu, d1=v1-mu, d2=v2-mu;
    float q = d0*d0 + d1*d1 + d2*d2;
    #pragma unroll
    for (int o=1;o<64;o<<=1) q += __shfl_xor(q, o, 64);
    __syncthreads();
    if ((tid&63)==0) red[tid>>6] = q;
    __syncthreads();
    float ms = (red[0]+red[1]+red[2]+red[3]) * (1.f/768.f);
    float inv = rsqrtf(ms + EPS);
    bf16* o_ = out + (long)r*768;
    float s0 = scalar_scale ? scale[0] : scale[tid];
    float s1 = scalar_scale ? s0 : scale[tid+256];
    float s2 = scalar_scale ? s0 : scale[tid+512];
    o_[tid]     = __float2bfloat16(d0*inv*s0 + bias[tid]);
    o_[tid+256] = __float2bfloat16(d1*inv*s1 + bias[tid+256]);
    o_[tid+512] = __float2bfloat16(d2*inv*s2 + bias[tid+512]);
}

extern "C" void kernel_launch(void* const* d_in, const int* in_sizes, int n_in,
                              void* d_out, int out_size, void* d_ws, size_t ws_size,
                              hipStream_t stream) {
    const float* x       = (const float*)d_in[0];
    const float* w_enc   = (const float*)d_in[1];
    const float* b_enc   = (const float*)d_in[2];
    const float* cls_tok = (const float*)d_in[3];
    const float* pos     = (const float*)d_in[4];
    const float* eln_g   = (const float*)d_in[5];
    const float* eln_b   = (const float*)d_in[6];
    const float* wq      = (const float*)d_in[7];
    const float* wk      = (const float*)d_in[8];
    const float* w_hop   = (const float*)d_in[9];
    const float* dln_w   = (const float*)d_in[10];
    const float* dln_b   = (const float*)d_in[11];
    const float* w_dec   = (const float*)d_in[12];
    const float* b_dec   = (const float*)d_in[13];
    float* out = (float*)d_out;

    float* t_  = (float*)d_ws;                    // [6400,768] fp32
    bf16* g_   = (bf16*)(t_ + 6400L*768);         // [6400,768]
    bf16* qkh  = g_ + 6400L*768;                  // [6400,4608] = q|k|h (aq|ak overwrite q|k)
    bf16* qT   = qkh + 6400L*4608;                // [384,64,256]
    bf16* kT   = qT + 384L*16384;                 // [384,64,256]
    bf16* B1   = kT + 384L*16384;                 // [4608,768]  wq|wk|whop
    bf16* B2   = B1 + 4608L*768;                  // [768,4608]  = B1^T
    bf16* we_  = B2 + 768L*4608;                  // [768,768]
    bf16* wd_  = we_ + 768L*768;                  // [768,768]

    dim3 blk(256);

    f2b_k<<<dim3((589824+255)/256),  blk, 0, stream>>>(wq,    B1,          589824);
    f2b_k<<<dim3((589824+255)/256),  blk, 0, stream>>>(wk,    B1+589824,   589824);
    f2b_k<<<dim3((2359296+255)/256), blk, 0, stream>>>(w_hop, B1+1179648, 2359296);
    f2b_k<<<dim3((589824+255)/256),  blk, 0, stream>>>(w_enc, we_,         589824);
    f2b_k<<<dim3((589824+255)/256),  blk, 0, stream>>>(w_dec, wd_,         589824);
    tr_k<<<dim3(144,24), blk, 0, stream>>>((const short*)B1, (short*)B2);
    padx_k<<<dim3((int)((6400L*768+255)/256)), blk, 0, stream>>>(x, g_);

    cls_k<<<dim3(96), blk, 0, stream>>>(cls_tok, pos, t_);
    gg_k<2><<<dim3(6,50), blk, 0, stream>>>((const short*)g_, 768, (const short*)we_, 768,
                                            t_, nullptr, 768, 768, 0, b_enc, pos);

    for (int step=0; step<12; step++){
        ln_k<<<dim3(6304), blk, 0, stream>>>(t_, g_, eln_g, eln_b, 1, 0);
        // [q|k|h] = g @ B1^T  (relu on h cols)
        gg_k<0><<<dim3(36,50), blk, 0, stream>>>((const short*)g_, 768, (const short*)B1, 768,
                                                 nullptr, qkh, 4608, 768, 1536, nullptr, nullptr);
        pack_k<<<dim3(384,4), blk, 0, stream>>>((const short*)qkh, (short*)qT, (short*)kT);
        attn_k<<<dim3(384), blk, 0, stream>>>((short*)qkh, (const short*)qT, (const short*)kT);
        // t += [aq|ak|h] @ B2^T   (split-K x2, atomicAdd)
        gg_k<1><<<dim3(6,50,2), blk, 0, stream>>>((const short*)qkh, 4608, (const short*)B2, 4608,
                                                  t_, nullptr, 768, 4608, 0, nullptr, nullptr);
    }

    ln_k<<<dim3(6272), blk, 0, stream>>>(t_, g_, dln_w, dln_b, 0, 1);
    gg_k<3><<<dim3(6,50), blk, 0, stream>>>((const short*)g_, 768, (const short*)wd_, 768,
                                            out, nullptr, 768, 768, 0, b_dec, nullptr);
}

// Round 6
// 3043.487 us; speedup vs baseline: 65.3194x; 65.3194x over previous
//
#include <hip/hip_runtime.h>
#include <hip/hip_bf16.h>

typedef __hip_bfloat16 bf16;
typedef short s8 __attribute__((ext_vector_type(8)));
typedef short sv4 __attribute__((ext_vector_type(4)));
typedef float f4 __attribute__((ext_vector_type(4)));

#define BETA 0.125f
#define EPS 1e-5f

__device__ __forceinline__ void gld16(const void* g, void* l){
    __builtin_amdgcn_global_load_lds(
        (const __attribute__((address_space(1))) void*)g,
        (__attribute__((address_space(3))) void*)l, 16, 0, 0);
}

// ---------- converts ----------
__global__ __launch_bounds__(256) void f2b_k(const float* __restrict__ in, bf16* __restrict__ out, long n){
    long i = (long)blockIdx.x*256 + threadIdx.x;
    if (i < n) out[i] = __float2bfloat16(in[i]);
}
__global__ __launch_bounds__(256) void padx_k(const float* __restrict__ x, bf16* __restrict__ xb){
    long i = (long)blockIdx.x*256 + threadIdx.x;
    if (i >= 6400L*768) return;
    long row = i / 768;
    xb[i] = (row < 6272) ? __float2bfloat16(x[i]) : __float2bfloat16(0.f);
}
__global__ __launch_bounds__(256) void tr_k(const short* __restrict__ Bi, short* __restrict__ Bo){
    __shared__ short t[32][33];
    int i0 = blockIdx.x*32, j0 = blockIdx.y*32;
    int li = threadIdx.x & 31, lj = threadIdx.x >> 5;
    #pragma unroll
    for (int r=0;r<4;r++) t[lj+8*r][li] = Bi[(long)(i0+lj+8*r)*768 + j0+li];
    __syncthreads();
    #pragma unroll
    for (int r=0;r<4;r++) Bo[(long)(j0+lj+8*r)*4608 + i0+li] = t[li][lj+8*r];
}

// ---------- cls row init ----------
__global__ __launch_bounds__(256) void cls_k(const float* __restrict__ cls, const float* __restrict__ pos,
                                             float* __restrict__ t){
    int i = blockIdx.x*256 + threadIdx.x;
    int b = i / 768, c = i % 768;
    t[((long)b*197)*768 + c] = cls[c] + pos[c];
}

// ---------- big MFMA GEMM: C = A[M,K] @ B[N,K]^T, LDS-staged (m97 structure) ----------
// 1D flat grid with group-8 m-swizzle: 8 consecutive blocks share n, span 8 m-rows
// (one per XCD -> per-XCD L2 keeps its A-tile hot across the n-sweep).
// MODE 0: C bf16, relu for col>=relu0 | MODE 1: C fp32 atomicAdd, split-K over blockIdx.z
// MODE 2: encode epilogue | MODE 3: decode epilogue
template<int MODE>
__global__ __launch_bounds__(256) void big_gemm(
    const short* __restrict__ A, int lda,
    const short* __restrict__ B, int ldb,
    float* __restrict__ Cf, bf16* __restrict__ Cb, int ldc,
    int K, int Nn, int Nm, int relu0,
    const float* __restrict__ bias, const float* __restrict__ pos)
{
    // ---- swizzle: flat -> (bm, bn) ----
    const int f = blockIdx.x;
    const int npg = 8*Nn;
    const int grp = f / npg;
    const int first_m = grp*8;
    const int gs = (Nm - first_m < 8) ? (Nm - first_m) : 8;
    const int rem = f % npg;
    const int bm = first_m + rem % gs;
    const int bn = rem / gs;

    __shared__ short lsA[4096];
    __shared__ short lsB[4096];
    const int tid = threadIdx.x;
    const int w = tid>>6, l = tid&63;
    const int m0 = bm*128, n0 = bn*128;
    const int srow = w*16 + (l>>2);
    const int scol = (l&3)*8;
    int koff, Ks;
    if (MODE==1){ Ks = K>>1; koff = blockIdx.z * Ks; }
    else        { Ks = K;    koff = 0; }
    const short* pa0 = A + (size_t)(m0+srow)*lda + koff + scol;
    const short* pa1 = A + (size_t)(m0+64+srow)*lda + koff + scol;
    const short* pb0 = B + (size_t)(n0+srow)*ldb + koff + scol;
    const short* pb1 = B + (size_t)(n0+64+srow)*ldb + koff + scol;
    short* la0 = lsA + w*512;
    short* la1 = lsA + 2048 + w*512;
    short* lb0 = lsB + w*512;
    short* lb1 = lsB + 2048 + w*512;
    const int wm = (w>>1)*64, wn = (w&1)*64;
    const int fr = l&15, fq = (l>>4)*8;
    f4 acc[4][4] = {};
    const int nk = Ks>>5;
    for (int kt=0; kt<nk; kt++){
        gld16(pa0, la0); gld16(pa1, la1);
        gld16(pb0, lb0); gld16(pb1, lb1);
        pa0 += 32; pa1 += 32; pb0 += 32; pb1 += 32;
        __syncthreads();
        s8 af[4], bfr[4];
        #pragma unroll
        for (int i=0;i<4;i++) af[i]  = *(const s8*)(lsA + (wm+i*16+fr)*32 + fq);
        #pragma unroll
        for (int j=0;j<4;j++) bfr[j] = *(const s8*)(lsB + (wn+j*16+fr)*32 + fq);
        #pragma unroll
        for (int i=0;i<4;i++)
            #pragma unroll
            for (int j=0;j<4;j++)
                acc[i][j] = __builtin_amdgcn_mfma_f32_16x16x32_bf16(af[i], bfr[j], acc[i][j], 0,0,0);
        __syncthreads();
    }
    const int er = (l>>4)*4;
    const int ec = l&15;
    #pragma unroll
    for (int i=0;i<4;i++){
        #pragma unroll
        for (int j=0;j<4;j++){
            int gr0 = m0 + wm + i*16 + er;
            int gc  = n0 + wn + j*16 + ec;
            #pragma unroll
            for (int r=0;r<4;r++){
                float v = acc[i][j][r];
                int gr = gr0 + r;
                if (MODE==0){
                    if (gc >= relu0) v = v>0.f ? v : 0.f;
                    Cb[(size_t)gr*ldc + gc] = __float2bfloat16(v);
                } else if (MODE==1){
                    atomicAdd(Cf + (size_t)gr*ldc + gc, v);
                } else if (MODE==2){
                    if (gr < 6272){
                        int b = gr/196, n = gr%196;
                        Cf[((size_t)b*197 + n + 1)*768 + gc] = v + bias[gc] + pos[(long)(n+1)*768+gc];
                    }
                } else {
                    if (gr < 6272) Cf[(size_t)gr*ldc + gc] = v + bias[gc];
                }
            }
        }
    }
}

// ---------- pack q^T / k^T : [384][64 z][256 m] bf16, zero-padded ----------
__global__ __launch_bounds__(256) void pack_k(const short* __restrict__ qkh,
                                              short* __restrict__ qT, short* __restrict__ kT){
    __shared__ short tq[64][65];
    __shared__ short tk[64][65];
    const int bh = blockIdx.x, b = bh/12, h = bh%12;
    const int mc = blockIdx.y*64;
    const int tid = threadIdx.x;
    #pragma unroll
    for (int e=0;e<16;e++){
        int i = tid + e*256; int r = i>>6, c = i&63;
        int mg = mc + r;
        short vq = 0, vk = 0;
        if (mg < 197){
            size_t base = (size_t)(b*197+mg)*4608 + h*64 + c;
            vq = qkh[base]; vk = qkh[base+768];
        }
        tq[r][c] = vq; tk[r][c] = vk;
    }
    __syncthreads();
    #pragma unroll
    for (int e=0;e<16;e++){
        int i = tid + e*256; int zr = i>>6, cm = i&63;
        size_t o = (size_t)bh*16384 + (size_t)zr*256 + mc + cm;
        qT[o] = tq[cm][zr];
        kT[o] = tk[cm][zr];
    }
}

// ---------- fused attention per (b,h) ----------
__global__ __launch_bounds__(256) void attn_k(
    short* __restrict__ qkh, const short* __restrict__ qT, const short* __restrict__ kT)
{
    __shared__ short Pl[64*232];
    __shared__ short Ptl[208*72];
    const int bh = blockIdx.x, b = bh/12, h = bh%12;
    const int tid = threadIdx.x, w = tid>>6, l = tid&63;
    const int lr = l&15, lq = l>>4;
    const size_t qcol = (size_t)h*64, kcol = 768 + qcol;
    const size_t rbase = (size_t)b*197*4608;
    const short* qTp = qT + (size_t)bh*16384;
    const short* kTp = kT + (size_t)bh*16384;

    for (int i=tid; i<64*16; i+=256){ int r=i>>4, c=208+(i&15); Pl[r*232+c]=0; }

    f4 ak[13];
    #pragma unroll
    for (int t=0;t<13;t++) ak[t] = (f4){0.f,0.f,0.f,0.f};

    for (int iter=0; iter<4; iter++){
        const int m0 = iter*64;
        f4 S[13];
        #pragma unroll
        for (int t=0;t<13;t++) S[t] = (f4){0.f,0.f,0.f,0.f};
        const int mrow = m0 + w*16 + lr;
        #pragma unroll
        for (int ks=0; ks<2; ks++){
            s8 af = *(const s8*)(qkh + rbase + (size_t)mrow*4608 + qcol + ks*32 + lq*8);
            #pragma unroll
            for (int t=0;t<13;t++){
                s8 bf = *(const s8*)(qkh + rbase + (size_t)(t*16+lr)*4608 + kcol + ks*32 + lq*8);
                S[t] = __builtin_amdgcn_mfma_f32_16x16x32_bf16(af, bf, S[t], 0,0,0);
            }
        }
        __syncthreads();
        const int mbase = w*16 + lq*4;
        #pragma unroll
        for (int r=0;r<4;r++){
            float mx = -1e30f;
            #pragma unroll
            for (int t=0;t<13;t++){
                float v = S[t][r]*BETA;
                if (t==12 && lr>=5) v = -1e30f;
                S[t][r] = v;
                mx = fmaxf(mx, v);
            }
            mx = fmaxf(mx, __shfl_xor(mx,1,64)); mx = fmaxf(mx, __shfl_xor(mx,2,64));
            mx = fmaxf(mx, __shfl_xor(mx,4,64)); mx = fmaxf(mx, __shfl_xor(mx,8,64));
            float sm = 0.f;
            #pragma unroll
            for (int t=0;t<13;t++){ float e = __expf(S[t][r]-mx); S[t][r]=e; sm+=e; }
            sm += __shfl_xor(sm,1,64); sm += __shfl_xor(sm,2,64);
            sm += __shfl_xor(sm,4,64); sm += __shfl_xor(sm,8,64);
            float inv = 1.f/sm;
            bool valid = (m0 + mbase + r) < 197;
            #pragma unroll
            for (int t=0;t<13;t++) S[t][r] = valid ? S[t][r]*inv : 0.f;
        }
        #pragma unroll
        for (int t=0;t<13;t++){
            int c = t*16 + lr;
            short pb[4];
            #pragma unroll
            for (int r=0;r<4;r++){
                bf16 bv = __float2bfloat16(S[t][r]);
                pb[r] = *(short*)&bv;
                Pl[(mbase+r)*232 + c] = pb[r];
            }
            *(sv4*)(Ptl + c*72 + mbase) = (sv4){pb[0],pb[1],pb[2],pb[3]};
        }
        __syncthreads();
        f4 aq[4];
        #pragma unroll
        for (int t=0;t<4;t++) aq[t] = (f4){0.f,0.f,0.f,0.f};
        #pragma unroll
        for (int ks=0; ks<7; ks++){
            s8 af = *(const s8*)(kTp + (w*16+lr)*256 + ks*32 + lq*8);
            #pragma unroll
            for (int mt=0;mt<4;mt++){
                s8 bf = *(const s8*)(Pl + (mt*16+lr)*232 + ks*32 + lq*8);
                aq[mt] = __builtin_amdgcn_mfma_f32_16x16x32_bf16(af, bf, aq[mt], 0,0,0);
            }
        }
        #pragma unroll
        for (int mt=0;mt<4;mt++){
            int mg = m0 + mt*16 + lr;
            if (mg < 197){
                sv4 pv;
                #pragma unroll
                for (int r=0;r<4;r++){ bf16 bv=__float2bfloat16(aq[mt][r]); pv[r]=*(short*)&bv; }
                *(sv4*)(qkh + rbase + (size_t)mg*4608 + qcol + w*16 + lq*4) = pv;
            }
        }
        #pragma unroll
        for (int ks=0; ks<2; ks++){
            s8 bf = *(const s8*)(qTp + (w*16+lr)*256 + m0 + ks*32 + lq*8);
            #pragma unroll
            for (int t=0;t<13;t++){
                s8 af = *(const s8*)(Ptl + (t*16+lr)*72 + ks*32 + lq*8);
                ak[t] = __builtin_amdgcn_mfma_f32_16x16x32_bf16(af, bf, ak[t], 0,0,0);
            }
        }
    }
    #pragma unroll
    for (int t=0;t<13;t++){
        #pragma unroll
        for (int r=0;r<4;r++){
            int n = t*16 + lq*4 + r;
            if (n < 197)
                *(bf16*)(qkh + rbase + (size_t)n*4608 + kcol + w*16 + lr) = __float2bfloat16(ak[t][r]);
        }
    }
}

// ---------- LN: fp32 in -> bf16 out ----------
__global__ __launch_bounds__(256) void ln_k(
    const float* __restrict__ in, bf16* __restrict__ out,
    const float* __restrict__ scale, const float* __restrict__ bias,
    int scalar_scale, int rowmap)
{
    int r = blockIdx.x;
    long src = rowmap ? ((long)(r/196)*197 + r%196 + 1) : (long)r;
    const float* x = in + src*768;
    int tid = threadIdx.x;
    float v0 = x[tid], v1 = x[tid+256], v2 = x[tid+512];
    __shared__ float red[4];
    float s = v0+v1+v2;
    #pragma unroll
    for (int o=1;o<64;o<<=1) s += __shfl_xor(s, o, 64);
    if ((tid&63)==0) red[tid>>6] = s;
    __syncthreads();
    float mu = (red[0]+red[1]+red[2]+red[3]) * (1.f/768.f);
    float d0=v0-mu, d1=v1-mu, d2=v2-mu;
    float q = d0*d0 + d1*d1 + d2*d2;
    #pragma unroll
    for (int o=1;o<64;o<<=1) q += __shfl_xor(q, o, 64);
    __syncthreads();
    if ((tid&63)==0) red[tid>>6] = q;
    __syncthreads();
    float ms = (red[0]+red[1]+red[2]+red[3]) * (1.f/768.f);
    float inv = rsqrtf(ms + EPS);
    bf16* o_ = out + (long)r*768;
    float s0 = scalar_scale ? scale[0] : scale[tid];
    float s1 = scalar_scale ? s0 : scale[tid+256];
    float s2 = scalar_scale ? s0 : scale[tid+512];
    o_[tid]     = __float2bfloat16(d0*inv*s0 + bias[tid]);
    o_[tid+256] = __float2bfloat16(d1*inv*s1 + bias[tid+256]);
    o_[tid+512] = __float2bfloat16(d2*inv*s2 + bias[tid+512]);
}

extern "C" void kernel_launch(void* const* d_in, const int* in_sizes, int n_in,
                              void* d_out, int out_size, void* d_ws, size_t ws_size,
                              hipStream_t stream) {
    const float* x       = (const float*)d_in[0];
    const float* w_enc   = (const float*)d_in[1];
    const float* b_enc   = (const float*)d_in[2];
    const float* cls_tok = (const float*)d_in[3];
    const float* pos     = (const float*)d_in[4];
    const float* eln_g   = (const float*)d_in[5];
    const float* eln_b   = (const float*)d_in[6];
    const float* wq      = (const float*)d_in[7];
    const float* wk      = (const float*)d_in[8];
    const float* w_hop   = (const float*)d_in[9];
    const float* dln_w   = (const float*)d_in[10];
    const float* dln_b   = (const float*)d_in[11];
    const float* w_dec   = (const float*)d_in[12];
    const float* b_dec   = (const float*)d_in[13];
    float* out = (float*)d_out;

    float* t_  = (float*)d_ws;                    // [6400,768] fp32
    bf16* g_   = (bf16*)(t_ + 6400L*768);         // [6400,768]
    bf16* qkh  = g_ + 6400L*768;                  // [6400,4608] = q|k|h (aq|ak overwrite q|k)
    bf16* qT   = qkh + 6400L*4608;                // [384,64,256]
    bf16* kT   = qT + 384L*16384;                 // [384,64,256]
    bf16* B1   = kT + 384L*16384;                 // [4608,768]  wq|wk|whop
    bf16* B2   = B1 + 4608L*768;                  // [768,4608]  = B1^T
    bf16* we_  = B2 + 768L*4608;                  // [768,768]
    bf16* wd_  = we_ + 768L*768;                  // [768,768]

    dim3 blk(256);

    f2b_k<<<dim3((589824+255)/256),  blk, 0, stream>>>(wq,    B1,          589824);
    f2b_k<<<dim3((589824+255)/256),  blk, 0, stream>>>(wk,    B1+589824,   589824);
    f2b_k<<<dim3((2359296+255)/256), blk, 0, stream>>>(w_hop, B1+1179648, 2359296);
    f2b_k<<<dim3((589824+255)/256),  blk, 0, stream>>>(w_enc, we_,         589824);
    f2b_k<<<dim3((589824+255)/256),  blk, 0, stream>>>(w_dec, wd_,         589824);
    tr_k<<<dim3(144,24), blk, 0, stream>>>((const short*)B1, (short*)B2);
    padx_k<<<dim3((int)((6400L*768+255)/256)), blk, 0, stream>>>(x, g_);

    cls_k<<<dim3(96), blk, 0, stream>>>(cls_tok, pos, t_);
    // encode: Nn=6, Nm=50
    big_gemm<2><<<dim3(300), blk, 0, stream>>>((const short*)g_, 768, (const short*)we_, 768,
                                               t_, nullptr, 768, 768, 6, 50, 0, b_enc, pos);

    for (int step=0; step<12; step++){
        ln_k<<<dim3(6304), blk, 0, stream>>>(t_, g_, eln_g, eln_b, 1, 0);
        // [q|k|h] = g @ B1^T  (relu on h cols); Nn=36, Nm=50
        big_gemm<0><<<dim3(1800), blk, 0, stream>>>((const short*)g_, 768, (const short*)B1, 768,
                                                    nullptr, qkh, 4608, 768, 36, 50, 1536, nullptr, nullptr);
        pack_k<<<dim3(384,4), blk, 0, stream>>>((const short*)qkh, (short*)qT, (short*)kT);
        attn_k<<<dim3(384), blk, 0, stream>>>((short*)qkh, (const short*)qT, (const short*)kT);
        // t += [aq|ak|h] @ B2^T  (split-K x2, atomicAdd); Nn=6, Nm=50
        big_gemm<1><<<dim3(300,1,2), blk, 0, stream>>>((const short*)qkh, 4608, (const short*)B2, 4608,
                                                       t_, nullptr, 768, 4608, 6, 50, 0, nullptr, nullptr);
    }

    ln_k<<<dim3(6272), blk, 0, stream>>>(t_, g_, dln_w, dln_b, 0, 1);
    big_gemm<3><<<dim3(300), blk, 0, stream>>>((const short*)g_, 768, (const short*)wd_, 768,
                                               out, nullptr, 768, 768, 6, 50, 0, b_dec, nullptr);
}

// Round 7
// 2736.581 us; speedup vs baseline: 72.6449x; 1.1121x over previous
//
#include <hip/hip_runtime.h>
#include <hip/hip_bf16.h>

typedef __hip_bfloat16 bf16;
typedef short s8 __attribute__((ext_vector_type(8)));
typedef short sv4 __attribute__((ext_vector_type(4)));
typedef float f4 __attribute__((ext_vector_type(4)));

#define BETA 0.125f
#define EPS 1e-5f

__device__ __forceinline__ void gld16(const void* g, void* l){
    __builtin_amdgcn_global_load_lds(
        (const __attribute__((address_space(1))) void*)g,
        (__attribute__((address_space(3))) void*)l, 16, 0, 0);
}

// ---------- converts ----------
__global__ __launch_bounds__(256) void f2b_k(const float* __restrict__ in, bf16* __restrict__ out, long n){
    long i = (long)blockIdx.x*256 + threadIdx.x;
    if (i < n) out[i] = __float2bfloat16(in[i]);
}
__global__ __launch_bounds__(256) void padx_k(const float* __restrict__ x, bf16* __restrict__ xb){
    long i = (long)blockIdx.x*256 + threadIdx.x;
    if (i >= 6400L*768) return;
    long row = i / 768;
    xb[i] = (row < 6272) ? __float2bfloat16(x[i]) : __float2bfloat16(0.f);
}
__global__ __launch_bounds__(256) void tr_k(const short* __restrict__ Bi, short* __restrict__ Bo){
    __shared__ short t[32][33];
    int i0 = blockIdx.x*32, j0 = blockIdx.y*32;
    int li = threadIdx.x & 31, lj = threadIdx.x >> 5;
    #pragma unroll
    for (int r=0;r<4;r++) t[lj+8*r][li] = Bi[(long)(i0+lj+8*r)*768 + j0+li];
    __syncthreads();
    #pragma unroll
    for (int r=0;r<4;r++) Bo[(long)(j0+lj+8*r)*4608 + i0+li] = t[li][lj+8*r];
}

// ---------- cls row init ----------
__global__ __launch_bounds__(256) void cls_k(const float* __restrict__ cls, const float* __restrict__ pos,
                                             float* __restrict__ t){
    int i = blockIdx.x*256 + threadIdx.x;
    int b = i / 768, c = i % 768;
    t[((long)b*197)*768 + c] = cls[c] + pos[c];
}

// ---------- big MFMA GEMM: C = A[M,K] @ B[N,K]^T, LDS-staged, BK=64 (2 panels) ----------
// 1D flat grid, group-16 m-swizzle for per-XCD L2 A-reuse.
// MODE 0: C bf16, relu col>=relu0 | MODE 1: C fp32 plain store to partial (z-offset zoff)
// MODE 2: encode epilogue | MODE 3: decode epilogue
template<int MODE>
__global__ __launch_bounds__(256) void big_gemm(
    const short* __restrict__ A, int lda,
    const short* __restrict__ B, int ldb,
    float* __restrict__ Cf, bf16* __restrict__ Cb, int ldc,
    int K, int Nn, int Nm, int relu0, long zoff,
    const float* __restrict__ bias, const float* __restrict__ pos)
{
    const int f = blockIdx.x;
    const int npg = 16*Nn;
    const int grp = f / npg;
    const int first_m = grp*16;
    const int gs = (Nm - first_m < 16) ? (Nm - first_m) : 16;
    const int rem = f % npg;
    const int bm = first_m + rem % gs;
    const int bn = rem / gs;

    __shared__ short lsA[8192];   // 2 panels x (128 rows x 32 cols)
    __shared__ short lsB[8192];
    const int tid = threadIdx.x;
    const int w = tid>>6, l = tid&63;
    const int m0 = bm*128, n0 = bn*128;
    const int srow = tid>>2;        // 0..63
    const int scol = (tid&3)*8;     // 0..24
    int koff, Ks;
    if (MODE==1){ Ks = K>>1; koff = blockIdx.z * Ks; Cf += (size_t)blockIdx.z * zoff; }
    else        { Ks = K;    koff = 0; }
    const short* pa = A + (size_t)(m0+srow)*lda + koff + scol;
    const short* pb = B + (size_t)(n0+srow)*ldb + koff + scol;
    short* laP = lsA + w*512;
    short* lbP = lsB + w*512;
    const int wm = (w>>1)*64, wn = (w&1)*64;
    const int fr = l&15, fq = (l>>4)*8;
    f4 acc[4][4] = {};
    const int nk = Ks>>6;
    for (int kt=0; kt<nk; kt++){
        const size_t ko = (size_t)kt*64;
        const size_t ra = 64*(size_t)lda, rb = 64*(size_t)ldb;
        gld16(pa + ko,           laP);
        gld16(pa + ko + ra,      laP + 2048);
        gld16(pa + ko + 32,      laP + 4096);
        gld16(pa + ko + 32 + ra, laP + 6144);
        gld16(pb + ko,           lbP);
        gld16(pb + ko + rb,      lbP + 2048);
        gld16(pb + ko + 32,      lbP + 4096);
        gld16(pb + ko + 32 + rb, lbP + 6144);
        __syncthreads();
        #pragma unroll
        for (int ks=0; ks<2; ks++){
            s8 af[4], bfr[4];
            #pragma unroll
            for (int i=0;i<4;i++) af[i]  = *(const s8*)(lsA + ks*4096 + (wm+i*16+fr)*32 + fq);
            #pragma unroll
            for (int j=0;j<4;j++) bfr[j] = *(const s8*)(lsB + ks*4096 + (wn+j*16+fr)*32 + fq);
            #pragma unroll
            for (int i=0;i<4;i++)
                #pragma unroll
                for (int j=0;j<4;j++)
                    acc[i][j] = __builtin_amdgcn_mfma_f32_16x16x32_bf16(af[i], bfr[j], acc[i][j], 0,0,0);
        }
        __syncthreads();
    }
    const int er = (l>>4)*4;
    const int ec = l&15;
    #pragma unroll
    for (int i=0;i<4;i++){
        #pragma unroll
        for (int j=0;j<4;j++){
            int gr0 = m0 + wm + i*16 + er;
            int gc  = n0 + wn + j*16 + ec;
            #pragma unroll
            for (int r=0;r<4;r++){
                float v = acc[i][j][r];
                int gr = gr0 + r;
                if (MODE==0){
                    if (gc >= relu0) v = v>0.f ? v : 0.f;
                    Cb[(size_t)gr*ldc + gc] = __float2bfloat16(v);
                } else if (MODE==1){
                    Cf[(size_t)gr*ldc + gc] = v;
                } else if (MODE==2){
                    if (gr < 6272){
                        int b = gr/196, n = gr%196;
                        Cf[((size_t)b*197 + n + 1)*768 + gc] = v + bias[gc] + pos[(long)(n+1)*768+gc];
                    }
                } else {
                    if (gr < 6272) Cf[(size_t)gr*ldc + gc] = v + bias[gc];
                }
            }
        }
    }
}

// ---------- pack q^T / k^T : [384][64 z][256 m] bf16, zero-padded ----------
__global__ __launch_bounds__(256) void pack_k(const short* __restrict__ qkh,
                                              short* __restrict__ qT, short* __restrict__ kT){
    __shared__ short tq[64][65];
    __shared__ short tk[64][65];
    const int bh = blockIdx.x, b = bh/12, h = bh%12;
    const int mc = blockIdx.y*64;
    const int tid = threadIdx.x;
    #pragma unroll
    for (int e=0;e<16;e++){
        int i = tid + e*256; int r = i>>6, c = i&63;
        int mg = mc + r;
        short vq = 0, vk = 0;
        if (mg < 197){
            size_t base = (size_t)(b*197+mg)*4608 + h*64 + c;
            vq = qkh[base]; vk = qkh[base+768];
        }
        tq[r][c] = vq; tk[r][c] = vk;
    }
    __syncthreads();
    #pragma unroll
    for (int e=0;e<16;e++){
        int i = tid + e*256; int zr = i>>6, cm = i&63;
        size_t o = (size_t)bh*16384 + (size_t)zr*256 + mc + cm;
        qT[o] = tq[cm][zr];
        kT[o] = tk[cm][zr];
    }
}

// ---------- fused attention per (b,h) ----------
__global__ __launch_bounds__(256) void attn_k(
    short* __restrict__ qkh, const short* __restrict__ qT, const short* __restrict__ kT)
{
    __shared__ short Pl[64*232];
    __shared__ short Ptl[208*72];
    const int bh = blockIdx.x, b = bh/12, h = bh%12;
    const int tid = threadIdx.x, w = tid>>6, l = tid&63;
    const int lr = l&15, lq = l>>4;
    const size_t qcol = (size_t)h*64, kcol = 768 + qcol;
    const size_t rbase = (size_t)b*197*4608;
    const short* qTp = qT + (size_t)bh*16384;
    const short* kTp = kT + (size_t)bh*16384;

    for (int i=tid; i<64*16; i+=256){ int r=i>>4, c=208+(i&15); Pl[r*232+c]=0; }

    f4 ak[13];
    #pragma unroll
    for (int t=0;t<13;t++) ak[t] = (f4){0.f,0.f,0.f,0.f};

    for (int iter=0; iter<4; iter++){
        const int m0 = iter*64;
        f4 S[13];
        #pragma unroll
        for (int t=0;t<13;t++) S[t] = (f4){0.f,0.f,0.f,0.f};
        const int mrow = m0 + w*16 + lr;
        #pragma unroll
        for (int ks=0; ks<2; ks++){
            s8 af = *(const s8*)(qkh + rbase + (size_t)mrow*4608 + qcol + ks*32 + lq*8);
            #pragma unroll
            for (int t=0;t<13;t++){
                s8 bf = *(const s8*)(qkh + rbase + (size_t)(t*16+lr)*4608 + kcol + ks*32 + lq*8);
                S[t] = __builtin_amdgcn_mfma_f32_16x16x32_bf16(af, bf, S[t], 0,0,0);
            }
        }
        __syncthreads();
        const int mbase = w*16 + lq*4;
        #pragma unroll
        for (int r=0;r<4;r++){
            float mx = -1e30f;
            #pragma unroll
            for (int t=0;t<13;t++){
                float v = S[t][r]*BETA;
                if (t==12 && lr>=5) v = -1e30f;
                S[t][r] = v;
                mx = fmaxf(mx, v);
            }
            mx = fmaxf(mx, __shfl_xor(mx,1,64)); mx = fmaxf(mx, __shfl_xor(mx,2,64));
            mx = fmaxf(mx, __shfl_xor(mx,4,64)); mx = fmaxf(mx, __shfl_xor(mx,8,64));
            float sm = 0.f;
            #pragma unroll
            for (int t=0;t<13;t++){ float e = __expf(S[t][r]-mx); S[t][r]=e; sm+=e; }
            sm += __shfl_xor(sm,1,64); sm += __shfl_xor(sm,2,64);
            sm += __shfl_xor(sm,4,64); sm += __shfl_xor(sm,8,64);
            float inv = 1.f/sm;
            bool valid = (m0 + mbase + r) < 197;
            #pragma unroll
            for (int t=0;t<13;t++) S[t][r] = valid ? S[t][r]*inv : 0.f;
        }
        #pragma unroll
        for (int t=0;t<13;t++){
            int c = t*16 + lr;
            short pb[4];
            #pragma unroll
            for (int r=0;r<4;r++){
                bf16 bv = __float2bfloat16(S[t][r]);
                pb[r] = *(short*)&bv;
                Pl[(mbase+r)*232 + c] = pb[r];
            }
            *(sv4*)(Ptl + c*72 + mbase) = (sv4){pb[0],pb[1],pb[2],pb[3]};
        }
        __syncthreads();
        f4 aq[4];
        #pragma unroll
        for (int t=0;t<4;t++) aq[t] = (f4){0.f,0.f,0.f,0.f};
        #pragma unroll
        for (int ks=0; ks<7; ks++){
            s8 af = *(const s8*)(kTp + (w*16+lr)*256 + ks*32 + lq*8);
            #pragma unroll
            for (int mt=0;mt<4;mt++){
                s8 bf = *(const s8*)(Pl + (mt*16+lr)*232 + ks*32 + lq*8);
                aq[mt] = __builtin_amdgcn_mfma_f32_16x16x32_bf16(af, bf, aq[mt], 0,0,0);
            }
        }
        #pragma unroll
        for (int mt=0;mt<4;mt++){
            int mg = m0 + mt*16 + lr;
            if (mg < 197){
                sv4 pv;
                #pragma unroll
                for (int r=0;r<4;r++){ bf16 bv=__float2bfloat16(aq[mt][r]); pv[r]=*(short*)&bv; }
                *(sv4*)(qkh + rbase + (size_t)mg*4608 + qcol + w*16 + lq*4) = pv;
            }
        }
        #pragma unroll
        for (int ks=0; ks<2; ks++){
            s8 bf = *(const s8*)(qTp + (w*16+lr)*256 + m0 + ks*32 + lq*8);
            #pragma unroll
            for (int t=0;t<13;t++){
                s8 af = *(const s8*)(Ptl + (t*16+lr)*72 + ks*32 + lq*8);
                ak[t] = __builtin_amdgcn_mfma_f32_16x16x32_bf16(af, bf, ak[t], 0,0,0);
            }
        }
    }
    #pragma unroll
    for (int t=0;t<13;t++){
        #pragma unroll
        for (int r=0;r<4;r++){
            int n = t*16 + lq*4 + r;
            if (n < 197)
                *(bf16*)(qkh + rbase + (size_t)n*4608 + kcol + w*16 + lr) = __float2bfloat16(ak[t][r]);
        }
    }
}

// ---------- LN (optionally folds split-K partials into t first) ----------
// addp: t_row += p0_row + p1_row (written back if writet). Then LN -> bf16 g.
__global__ __launch_bounds__(256) void ln_k(
    float* __restrict__ in, bf16* __restrict__ out,
    const float* __restrict__ p0, const float* __restrict__ p1,
    const float* __restrict__ scale, const float* __restrict__ bias,
    int scalar_scale, int rowmap, int addp, int writet)
{
    int r = blockIdx.x;
    long src = rowmap ? ((long)(r/196)*197 + r%196 + 1) : (long)r;
    float* xr = in + src*768;
    int tid = threadIdx.x;
    float v0 = xr[tid], v1 = xr[tid+256], v2 = xr[tid+512];
    if (addp){
        const float* a = p0 + src*768;
        const float* b = p1 + src*768;
        v0 += a[tid]     + b[tid];
        v1 += a[tid+256] + b[tid+256];
        v2 += a[tid+512] + b[tid+512];
        if (writet){ xr[tid]=v0; xr[tid+256]=v1; xr[tid+512]=v2; }
    }
    __shared__ float red[4];
    float s = v0+v1+v2;
    #pragma unroll
    for (int o=1;o<64;o<<=1) s += __shfl_xor(s, o, 64);
    if ((tid&63)==0) red[tid>>6] = s;
    __syncthreads();
    float mu = (red[0]+red[1]+red[2]+red[3]) * (1.f/768.f);
    float d0=v0-mu, d1=v1-mu, d2=v2-mu;
    float q = d0*d0 + d1*d1 + d2*d2;
    #pragma unroll
    for (int o=1;o<64;o<<=1) q += __shfl_xor(q, o, 64);
    __syncthreads();
    if ((tid&63)==0) red[tid>>6] = q;
    __syncthreads();
    float ms = (red[0]+red[1]+red[2]+red[3]) * (1.f/768.f);
    float inv = rsqrtf(ms + EPS);
    bf16* o_ = out + (long)r*768;
    float s0 = scalar_scale ? scale[0] : scale[tid];
    float s1 = scalar_scale ? s0 : scale[tid+256];
    float s2 = scalar_scale ? s0 : scale[tid+512];
    o_[tid]     = __float2bfloat16(d0*inv*s0 + bias[tid]);
    o_[tid+256] = __float2bfloat16(d1*inv*s1 + bias[tid+256]);
    o_[tid+512] = __float2bfloat16(d2*inv*s2 + bias[tid+512]);
}

extern "C" void kernel_launch(void* const* d_in, const int* in_sizes, int n_in,
                              void* d_out, int out_size, void* d_ws, size_t ws_size,
                              hipStream_t stream) {
    const float* x       = (const float*)d_in[0];
    const float* w_enc   = (const float*)d_in[1];
    const float* b_enc   = (const float*)d_in[2];
    const float* cls_tok = (const float*)d_in[3];
    const float* pos     = (const float*)d_in[4];
    const float* eln_g   = (const float*)d_in[5];
    const float* eln_b   = (const float*)d_in[6];
    const float* wq      = (const float*)d_in[7];
    const float* wk      = (const float*)d_in[8];
    const float* w_hop   = (const float*)d_in[9];
    const float* dln_w   = (const float*)d_in[10];
    const float* dln_b   = (const float*)d_in[11];
    const float* w_dec   = (const float*)d_in[12];
    const float* b_dec   = (const float*)d_in[13];
    float* out = (float*)d_out;

    float* t_  = (float*)d_ws;                    // [6400,768] fp32
    bf16* g_   = (bf16*)(t_ + 6400L*768);         // [6400,768]
    bf16* qkh  = g_ + 6400L*768;                  // [6400,4608] = q|k|h (aq|ak overwrite q|k)
    bf16* qT   = qkh + 6400L*4608;                // [384,64,256]
    bf16* kT   = qT + 384L*16384;                 // [384,64,256]
    float* p0  = (float*)(kT + 384L*16384);       // [6400,768] split-K partial z=0
    float* p1  = p0 + 6400L*768;                  // [6400,768] split-K partial z=1
    bf16* B1   = (bf16*)(p1 + 6400L*768);         // [4608,768]  wq|wk|whop
    bf16* B2   = B1 + 4608L*768;                  // [768,4608]  = B1^T
    bf16* we_  = B2 + 768L*4608;                  // [768,768]
    bf16* wd_  = we_ + 768L*768;                  // [768,768]
    // total ~169.5 MB

    dim3 blk(256);
    const long ZOFF = 6400L*768;

    f2b_k<<<dim3((589824+255)/256),  blk, 0, stream>>>(wq,    B1,          589824);
    f2b_k<<<dim3((589824+255)/256),  blk, 0, stream>>>(wk,    B1+589824,   589824);
    f2b_k<<<dim3((2359296+255)/256), blk, 0, stream>>>(w_hop, B1+1179648, 2359296);
    f2b_k<<<dim3((589824+255)/256),  blk, 0, stream>>>(w_enc, we_,         589824);
    f2b_k<<<dim3((589824+255)/256),  blk, 0, stream>>>(w_dec, wd_,         589824);
    tr_k<<<dim3(144,24), blk, 0, stream>>>((const short*)B1, (short*)B2);
    padx_k<<<dim3((int)((6400L*768+255)/256)), blk, 0, stream>>>(x, g_);

    cls_k<<<dim3(96), blk, 0, stream>>>(cls_tok, pos, t_);
    // encode: Nn=6, Nm=50
    big_gemm<2><<<dim3(300), blk, 0, stream>>>((const short*)g_, 768, (const short*)we_, 768,
                                               t_, nullptr, 768, 768, 6, 50, 0, 0, b_enc, pos);

    for (int step=0; step<12; step++){
        // LN; for step>0 fold previous split-K partials into t first
        ln_k<<<dim3(6304), blk, 0, stream>>>(t_, g_, p0, p1, eln_g, eln_b, 1, 0, step>0, 1);
        // [q|k|h] = g @ B1^T  (relu on h cols); Nn=36, Nm=50
        big_gemm<0><<<dim3(1800), blk, 0, stream>>>((const short*)g_, 768, (const short*)B1, 768,
                                                    nullptr, qkh, 4608, 768, 36, 50, 1536, 0, nullptr, nullptr);
        pack_k<<<dim3(384,4), blk, 0, stream>>>((const short*)qkh, (short*)qT, (short*)kT);
        attn_k<<<dim3(384), blk, 0, stream>>>((short*)qkh, (const short*)qT, (const short*)kT);
        // p0/p1 = [aq|ak|h] @ B2^T halves (split-K x2, plain stores); Nn=6, Nm=50
        big_gemm<1><<<dim3(300,1,2), blk, 0, stream>>>((const short*)qkh, 4608, (const short*)B2, 4608,
                                                       p0, nullptr, 768, 4608, 6, 50, 0, ZOFF, nullptr, nullptr);
    }

    // decode LN folds the last step's partials (no need to write t back)
    ln_k<<<dim3(6272), blk, 0, stream>>>(t_, g_, p0, p1, dln_w, dln_b, 0, 1, 1, 0);
    big_gemm<3><<<dim3(300), blk, 0, stream>>>((const short*)g_, 768, (const short*)wd_, 768,
                                               out, nullptr, 768, 768, 6, 50, 0, 0, b_dec, nullptr);
}

// Round 8
// 2638.270 us; speedup vs baseline: 75.3519x; 1.0373x over previous
//
#include <hip/hip_runtime.h>
#include <hip/hip_bf16.h>

typedef __hip_bfloat16 bf16;
typedef short s8 __attribute__((ext_vector_type(8)));
typedef short sv4 __attribute__((ext_vector_type(4)));
typedef float f4 __attribute__((ext_vector_type(4)));

#define BETA 0.125f
#define EPS 1e-5f

__device__ __forceinline__ void gld16(const void* g, void* l){
    __builtin_amdgcn_global_load_lds(
        (const __attribute__((address_space(1))) void*)g,
        (__attribute__((address_space(3))) void*)l, 16, 0, 0);
}

// ---------- converts ----------
__global__ __launch_bounds__(256) void f2b_k(const float* __restrict__ in, bf16* __restrict__ out, long n){
    long i = (long)blockIdx.x*256 + threadIdx.x;
    if (i < n) out[i] = __float2bfloat16(in[i]);
}
__global__ __launch_bounds__(256) void padx_k(const float* __restrict__ x, bf16* __restrict__ xb){
    long i = (long)blockIdx.x*256 + threadIdx.x;
    if (i >= 6400L*768) return;
    long row = i / 768;
    xb[i] = (row < 6272) ? __float2bfloat16(x[i]) : __float2bfloat16(0.f);
}
__global__ __launch_bounds__(256) void tr_k(const short* __restrict__ Bi, short* __restrict__ Bo){
    __shared__ short t[32][33];
    int i0 = blockIdx.x*32, j0 = blockIdx.y*32;
    int li = threadIdx.x & 31, lj = threadIdx.x >> 5;
    #pragma unroll
    for (int r=0;r<4;r++) t[lj+8*r][li] = Bi[(long)(i0+lj+8*r)*768 + j0+li];
    __syncthreads();
    #pragma unroll
    for (int r=0;r<4;r++) Bo[(long)(j0+lj+8*r)*4608 + i0+li] = t[li][lj+8*r];
}

// ---------- cls row init ----------
__global__ __launch_bounds__(256) void cls_k(const float* __restrict__ cls, const float* __restrict__ pos,
                                             float* __restrict__ t){
    int i = blockIdx.x*256 + threadIdx.x;
    int b = i / 768, c = i % 768;
    t[((long)b*197)*768 + c] = cls[c] + pos[c];
}

// ---------- big MFMA GEMM: C = A[M,K] @ B[N,K]^T, LDS-staged, BK=64, bank-swizzled ----------
// LDS quadrant swizzle: global quadrant q of row r stored at LDS quadrant (q + (r>>1))&3.
// Staging realizes this by permuting WHICH global 16B each lane fetches (LDS dest is
// fixed at lane*16B by global_load_lds). Fragment reads use qs = (lq + (fr>>1))&3.
// 1D flat grid, group-16 m-swizzle for per-XCD L2 A-reuse.
// MODE 0: C bf16, relu col>=relu0 | MODE 1: C fp32 plain store to partial (z-offset zoff)
// MODE 2: encode epilogue | MODE 3: decode epilogue
template<int MODE>
__global__ __launch_bounds__(256) void big_gemm(
    const short* __restrict__ A, int lda,
    const short* __restrict__ B, int ldb,
    float* __restrict__ Cf, bf16* __restrict__ Cb, int ldc,
    int K, int Nn, int Nm, int relu0, long zoff,
    const float* __restrict__ bias, const float* __restrict__ pos)
{
    const int f = blockIdx.x;
    const int npg = 16*Nn;
    const int grp = f / npg;
    const int first_m = grp*16;
    const int gs = (Nm - first_m < 16) ? (Nm - first_m) : 16;
    const int rem = f % npg;
    const int bm = first_m + rem % gs;
    const int bn = rem / gs;

    __shared__ short lsA[8192];   // 2 k-panels x (128 rows x 32 cols)
    __shared__ short lsB[8192];
    const int tid = threadIdx.x;
    const int w = tid>>6, l = tid&63;
    const int m0 = bm*128, n0 = bn*128;
    const int srow = tid>>2;                       // 0..63 (global row within half)
    const int qglob = ((tid&3) - (tid>>3)) & 3;    // swizzled source quadrant
    const int scol = qglob*8;                      // shorts
    int koff, Ks;
    if (MODE==1){ Ks = K>>1; koff = blockIdx.z * Ks; Cf += (size_t)blockIdx.z * zoff; }
    else        { Ks = K;    koff = 0; }
    const short* pa = A + (size_t)(m0+srow)*lda + koff + scol;
    const short* pb = B + (size_t)(n0+srow)*ldb + koff + scol;
    short* laP = lsA + w*512;
    short* lbP = lsB + w*512;
    const int wm = (w>>1)*64, wn = (w&1)*64;
    const int fr = l&15, fq = ((l>>4) + (fr>>1) & 3)*8;   // swizzled read quadrant
    f4 acc[4][4] = {};
    const int nk = Ks>>6;
    for (int kt=0; kt<nk; kt++){
        const size_t ko = (size_t)kt*64;
        const size_t ra = 64*(size_t)lda, rb = 64*(size_t)ldb;
        gld16(pa + ko,           laP);
        gld16(pa + ko + ra,      laP + 2048);
        gld16(pa + ko + 32,      laP + 4096);
        gld16(pa + ko + 32 + ra, laP + 6144);
        gld16(pb + ko,           lbP);
        gld16(pb + ko + rb,      lbP + 2048);
        gld16(pb + ko + 32,      lbP + 4096);
        gld16(pb + ko + 32 + rb, lbP + 6144);
        __syncthreads();
        #pragma unroll
        for (int ks=0; ks<2; ks++){
            s8 af[4], bfr[4];
            #pragma unroll
            for (int i=0;i<4;i++) af[i]  = *(const s8*)(lsA + ks*4096 + (wm+i*16+fr)*32 + fq);
            #pragma unroll
            for (int j=0;j<4;j++) bfr[j] = *(const s8*)(lsB + ks*4096 + (wn+j*16+fr)*32 + fq);
            #pragma unroll
            for (int i=0;i<4;i++)
                #pragma unroll
                for (int j=0;j<4;j++)
                    acc[i][j] = __builtin_amdgcn_mfma_f32_16x16x32_bf16(af[i], bfr[j], acc[i][j], 0,0,0);
        }
        __syncthreads();
    }
    const int er = (l>>4)*4;
    const int ec = l&15;
    #pragma unroll
    for (int i=0;i<4;i++){
        #pragma unroll
        for (int j=0;j<4;j++){
            int gr0 = m0 + wm + i*16 + er;
            int gc  = n0 + wn + j*16 + ec;
            #pragma unroll
            for (int r=0;r<4;r++){
                float v = acc[i][j][r];
                int gr = gr0 + r;
                if (MODE==0){
                    if (gc >= relu0) v = v>0.f ? v : 0.f;
                    Cb[(size_t)gr*ldc + gc] = __float2bfloat16(v);
                } else if (MODE==1){
                    Cf[(size_t)gr*ldc + gc] = v;
                } else if (MODE==2){
                    if (gr < 6272){
                        int b = gr/196, n = gr%196;
                        Cf[((size_t)b*197 + n + 1)*768 + gc] = v + bias[gc] + pos[(long)(n+1)*768+gc];
                    }
                } else {
                    if (gr < 6272) Cf[(size_t)gr*ldc + gc] = v + bias[gc];
                }
            }
        }
    }
}

// ---------- pack q^T / k^T : [384][64 z][256 m] bf16, zero-padded ----------
__global__ __launch_bounds__(256) void pack_k(const short* __restrict__ qkh,
                                              short* __restrict__ qT, short* __restrict__ kT){
    __shared__ short tq[64][65];
    __shared__ short tk[64][65];
    const int bh = blockIdx.x, b = bh/12, h = bh%12;
    const int mc = blockIdx.y*64;
    const int tid = threadIdx.x;
    #pragma unroll
    for (int e=0;e<16;e++){
        int i = tid + e*256; int r = i>>6, c = i&63;
        int mg = mc + r;
        short vq = 0, vk = 0;
        if (mg < 197){
            size_t base = (size_t)(b*197+mg)*4608 + h*64 + c;
            vq = qkh[base]; vk = qkh[base+768];
        }
        tq[r][c] = vq; tk[r][c] = vk;
    }
    __syncthreads();
    #pragma unroll
    for (int e=0;e<16;e++){
        int i = tid + e*256; int zr = i>>6, cm = i&63;
        size_t o = (size_t)bh*16384 + (size_t)zr*256 + mc + cm;
        qT[o] = tq[cm][zr];
        kT[o] = tk[cm][zr];
    }
}

// ---------- fused attention per (b,h) ----------
__global__ __launch_bounds__(256) void attn_k(
    short* __restrict__ qkh, const short* __restrict__ qT, const short* __restrict__ kT)
{
    __shared__ short Pl[64*232];
    __shared__ short Ptl[208*72];
    const int bh = blockIdx.x, b = bh/12, h = bh%12;
    const int tid = threadIdx.x, w = tid>>6, l = tid&63;
    const int lr = l&15, lq = l>>4;
    const size_t qcol = (size_t)h*64, kcol = 768 + qcol;
    const size_t rbase = (size_t)b*197*4608;
    const short* qTp = qT + (size_t)bh*16384;
    const short* kTp = kT + (size_t)bh*16384;

    for (int i=tid; i<64*16; i+=256){ int r=i>>4, c=208+(i&15); Pl[r*232+c]=0; }

    f4 ak[13];
    #pragma unroll
    for (int t=0;t<13;t++) ak[t] = (f4){0.f,0.f,0.f,0.f};

    for (int iter=0; iter<4; iter++){
        const int m0 = iter*64;
        f4 S[13];
        #pragma unroll
        for (int t=0;t<13;t++) S[t] = (f4){0.f,0.f,0.f,0.f};
        const int mrow = m0 + w*16 + lr;
        #pragma unroll
        for (int ks=0; ks<2; ks++){
            s8 af = *(const s8*)(qkh + rbase + (size_t)mrow*4608 + qcol + ks*32 + lq*8);
            #pragma unroll
            for (int t=0;t<13;t++){
                s8 bf = *(const s8*)(qkh + rbase + (size_t)(t*16+lr)*4608 + kcol + ks*32 + lq*8);
                S[t] = __builtin_amdgcn_mfma_f32_16x16x32_bf16(af, bf, S[t], 0,0,0);
            }
        }
        __syncthreads();
        const int mbase = w*16 + lq*4;
        #pragma unroll
        for (int r=0;r<4;r++){
            float mx = -1e30f;
            #pragma unroll
            for (int t=0;t<13;t++){
                float v = S[t][r]*BETA;
                if (t==12 && lr>=5) v = -1e30f;
                S[t][r] = v;
                mx = fmaxf(mx, v);
            }
            mx = fmaxf(mx, __shfl_xor(mx,1,64)); mx = fmaxf(mx, __shfl_xor(mx,2,64));
            mx = fmaxf(mx, __shfl_xor(mx,4,64)); mx = fmaxf(mx, __shfl_xor(mx,8,64));
            float sm = 0.f;
            #pragma unroll
            for (int t=0;t<13;t++){ float e = __expf(S[t][r]-mx); S[t][r]=e; sm+=e; }
            sm += __shfl_xor(sm,1,64); sm += __shfl_xor(sm,2,64);
            sm += __shfl_xor(sm,4,64); sm += __shfl_xor(sm,8,64);
            float inv = 1.f/sm;
            bool valid = (m0 + mbase + r) < 197;
            #pragma unroll
            for (int t=0;t<13;t++) S[t][r] = valid ? S[t][r]*inv : 0.f;
        }
        #pragma unroll
        for (int t=0;t<13;t++){
            int c = t*16 + lr;
            short pb[4];
            #pragma unroll
            for (int r=0;r<4;r++){
                bf16 bv = __float2bfloat16(S[t][r]);
                pb[r] = *(short*)&bv;
                Pl[(mbase+r)*232 + c] = pb[r];
            }
            *(sv4*)(Ptl + c*72 + mbase) = (sv4){pb[0],pb[1],pb[2],pb[3]};
        }
        __syncthreads();
        f4 aq[4];
        #pragma unroll
        for (int t=0;t<4;t++) aq[t] = (f4){0.f,0.f,0.f,0.f};
        #pragma unroll
        for (int ks=0; ks<7; ks++){
            s8 af = *(const s8*)(kTp + (w*16+lr)*256 + ks*32 + lq*8);
            #pragma unroll
            for (int mt=0;mt<4;mt++){
                s8 bf = *(const s8*)(Pl + (mt*16+lr)*232 + ks*32 + lq*8);
                aq[mt] = __builtin_amdgcn_mfma_f32_16x16x32_bf16(af, bf, aq[mt], 0,0,0);
            }
        }
        #pragma unroll
        for (int mt=0;mt<4;mt++){
            int mg = m0 + mt*16 + lr;
            if (mg < 197){
                sv4 pv;
                #pragma unroll
                for (int r=0;r<4;r++){ bf16 bv=__float2bfloat16(aq[mt][r]); pv[r]=*(short*)&bv; }
                *(sv4*)(qkh + rbase + (size_t)mg*4608 + qcol + w*16 + lq*4) = pv;
            }
        }
        #pragma unroll
        for (int ks=0; ks<2; ks++){
            s8 bf = *(const s8*)(qTp + (w*16+lr)*256 + m0 + ks*32 + lq*8);
            #pragma unroll
            for (int t=0;t<13;t++){
                s8 af = *(const s8*)(Ptl + (t*16+lr)*72 + ks*32 + lq*8);
                ak[t] = __builtin_amdgcn_mfma_f32_16x16x32_bf16(af, bf, ak[t], 0,0,0);
            }
        }
    }
    #pragma unroll
    for (int t=0;t<13;t++){
        #pragma unroll
        for (int r=0;r<4;r++){
            int n = t*16 + lq*4 + r;
            if (n < 197)
                *(bf16*)(qkh + rbase + (size_t)n*4608 + kcol + w*16 + lr) = __float2bfloat16(ak[t][r]);
        }
    }
}

// ---------- LN (optionally folds split-K partials into t first) ----------
__global__ __launch_bounds__(256) void ln_k(
    float* __restrict__ in, bf16* __restrict__ out,
    const float* __restrict__ p0, const float* __restrict__ p1,
    const float* __restrict__ scale, const float* __restrict__ bias,
    int scalar_scale, int rowmap, int addp, int writet)
{
    int r = blockIdx.x;
    long src = rowmap ? ((long)(r/196)*197 + r%196 + 1) : (long)r;
    float* xr = in + src*768;
    int tid = threadIdx.x;
    float v0 = xr[tid], v1 = xr[tid+256], v2 = xr[tid+512];
    if (addp){
        const float* a = p0 + src*768;
        const float* b = p1 + src*768;
        v0 += a[tid]     + b[tid];
        v1 += a[tid+256] + b[tid+256];
        v2 += a[tid+512] + b[tid+512];
        if (writet){ xr[tid]=v0; xr[tid+256]=v1; xr[tid+512]=v2; }
    }
    __shared__ float red[4];
    float s = v0+v1+v2;
    #pragma unroll
    for (int o=1;o<64;o<<=1) s += __shfl_xor(s, o, 64);
    if ((tid&63)==0) red[tid>>6] = s;
    __syncthreads();
    float mu = (red[0]+red[1]+red[2]+red[3]) * (1.f/768.f);
    float d0=v0-mu, d1=v1-mu, d2=v2-mu;
    float q = d0*d0 + d1*d1 + d2*d2;
    #pragma unroll
    for (int o=1;o<64;o<<=1) q += __shfl_xor(q, o, 64);
    __syncthreads();
    if ((tid&63)==0) red[tid>>6] = q;
    __syncthreads();
    float ms = (red[0]+red[1]+red[2]+red[3]) * (1.f/768.f);
    float inv = rsqrtf(ms + EPS);
    bf16* o_ = out + (long)r*768;
    float s0 = scalar_scale ? scale[0] : scale[tid];
    float s1 = scalar_scale ? s0 : scale[tid+256];
    float s2 = scalar_scale ? s0 : scale[tid+512];
    o_[tid]     = __float2bfloat16(d0*inv*s0 + bias[tid]);
    o_[tid+256] = __float2bfloat16(d1*inv*s1 + bias[tid+256]);
    o_[tid+512] = __float2bfloat16(d2*inv*s2 + bias[tid+512]);
}

extern "C" void kernel_launch(void* const* d_in, const int* in_sizes, int n_in,
                              void* d_out, int out_size, void* d_ws, size_t ws_size,
                              hipStream_t stream) {
    const float* x       = (const float*)d_in[0];
    const float* w_enc   = (const float*)d_in[1];
    const float* b_enc   = (const float*)d_in[2];
    const float* cls_tok = (const float*)d_in[3];
    const float* pos     = (const float*)d_in[4];
    const float* eln_g   = (const float*)d_in[5];
    const float* eln_b   = (const float*)d_in[6];
    const float* wq      = (const float*)d_in[7];
    const float* wk      = (const float*)d_in[8];
    const float* w_hop   = (const float*)d_in[9];
    const float* dln_w   = (const float*)d_in[10];
    const float* dln_b   = (const float*)d_in[11];
    const float* w_dec   = (const float*)d_in[12];
    const float* b_dec   = (const float*)d_in[13];
    float* out = (float*)d_out;

    float* t_  = (float*)d_ws;                    // [6400,768] fp32
    bf16* g_   = (bf16*)(t_ + 6400L*768);         // [6400,768]
    bf16* qkh  = g_ + 6400L*768;                  // [6400,4608] = q|k|h (aq|ak overwrite q|k)
    bf16* qT   = qkh + 6400L*4608;                // [384,64,256]
    bf16* kT   = qT + 384L*16384;                 // [384,64,256]
    float* p0  = (float*)(kT + 384L*16384);       // [6400,768] split-K partial z=0
    float* p1  = p0 + 6400L*768;                  // [6400,768] split-K partial z=1
    bf16* B1   = (bf16*)(p1 + 6400L*768);         // [4608,768]  wq|wk|whop
    bf16* B2   = B1 + 4608L*768;                  // [768,4608]  = B1^T
    bf16* we_  = B2 + 768L*4608;                  // [768,768]
    bf16* wd_  = we_ + 768L*768;                  // [768,768]

    dim3 blk(256);
    const long ZOFF = 6400L*768;

    f2b_k<<<dim3((589824+255)/256),  blk, 0, stream>>>(wq,    B1,          589824);
    f2b_k<<<dim3((589824+255)/256),  blk, 0, stream>>>(wk,    B1+589824,   589824);
    f2b_k<<<dim3((2359296+255)/256), blk, 0, stream>>>(w_hop, B1+1179648, 2359296);
    f2b_k<<<dim3((589824+255)/256),  blk, 0, stream>>>(w_enc, we_,         589824);
    f2b_k<<<dim3((589824+255)/256),  blk, 0, stream>>>(w_dec, wd_,         589824);
    tr_k<<<dim3(144,24), blk, 0, stream>>>((const short*)B1, (short*)B2);
    padx_k<<<dim3((int)((6400L*768+255)/256)), blk, 0, stream>>>(x, g_);

    cls_k<<<dim3(96), blk, 0, stream>>>(cls_tok, pos, t_);
    big_gemm<2><<<dim3(300), blk, 0, stream>>>((const short*)g_, 768, (const short*)we_, 768,
                                               t_, nullptr, 768, 768, 6, 50, 0, 0, b_enc, pos);

    for (int step=0; step<12; step++){
        ln_k<<<dim3(6304), blk, 0, stream>>>(t_, g_, p0, p1, eln_g, eln_b, 1, 0, step>0, 1);
        big_gemm<0><<<dim3(1800), blk, 0, stream>>>((const short*)g_, 768, (const short*)B1, 768,
                                                    nullptr, qkh, 4608, 768, 36, 50, 1536, 0, nullptr, nullptr);
        pack_k<<<dim3(384,4), blk, 0, stream>>>((const short*)qkh, (short*)qT, (short*)kT);
        attn_k<<<dim3(384), blk, 0, stream>>>((short*)qkh, (const short*)qT, (const short*)kT);
        big_gemm<1><<<dim3(300,1,2), blk, 0, stream>>>((const short*)qkh, 4608, (const short*)B2, 4608,
                                                       p0, nullptr, 768, 4608, 6, 50, 0, ZOFF, nullptr, nullptr);
    }

    ln_k<<<dim3(6272), blk, 0, stream>>>(t_, g_, p0, p1, dln_w, dln_b, 0, 1, 1, 0);
    big_gemm<3><<<dim3(300), blk, 0, stream>>>((const short*)g_, 768, (const short*)wd_, 768,
                                               out, nullptr, 768, 768, 6, 50, 0, 0, b_dec, nullptr);
}